// Round 1
// 208.612 us; speedup vs baseline: 1.0132x; 1.0132x over previous
//
#include <hip/hip_runtime.h>
#include <hip/hip_bf16.h>
#include <math.h>

// Problem constants (setup_inputs: B=4, T=1024)
#define BB 4
#define TT 1024
#define BT 4096

// Workspace layout (fp32 offsets in floats)
#define OFF_BLOCKS 0          // [BT][64]  blocks in [i*4+e] channel order
#define OFF_QKVB   262144     // [16][BT][12] per-block qkv (dead after k_blk_part)
#define OFF_RECVP  262144     // [B][1024 k][128 src] recv partials (aliases QKVB, 2 MB)
#define OFF_ALLB   1048576    // [BT][64]  per-block MHA output (all_blocks)
#define OFF_QKVC   1310720    // [BT][192] cross qkv
#define OFF_LC     2097152    // [B*8][T]  (unused; kept for layout stability)
#define OFF_ACCC   2129920    // [B*8][T][8] cross PV (normalized by l)
#define OFF_LN1    2396160    // [BT][64]  post-LN1 activations
#define OFF_PARAMS 2658304    // repacked fp32 weights (see P_* below)
#define WS_FLOATS  2708624

// Param sub-offsets (floats, relative to OFF_PARAMS)
#define P_W1T    0        // [64 j][256 h]
#define P_W2T    16384    // [256 k][64 j]
#define P_WQCT   32768    // [64 j][192 c]
#define P_WOCT   45056    // [64 m][64 j]
#define P_WOBLK  49152    // [16 i][4 j][4 m]
#define P_BOBLK  49408
#define P_BQC    49472
#define P_BOC    49664
#define P_G1     49728
#define P_BE1    49792
#define P_B1     49856
#define P_B2     50112
#define P_G2     50176
#define P_BE2    50240
#define P_SAL    50304
#define P_TOTAL  50320

__device__ inline float rcpf(float x) { return __builtin_amdgcn_rcpf(x); }

// ---------- in-block dtype detection (wave-uniform) ----------
__device__ inline bool detect_bf16(const void* M) {
  const unsigned short* h = (const unsigned short*)M;
  unsigned short v = h[threadIdx.x & 63];
  int e = (v >> 7) & 0xff;
  unsigned long long m = __ballot((e >= 90) && (e <= 141));
  return __popcll(m) >= 58;
}

template <bool ISBF>
__device__ inline float ldf(const void* p, int i) {
  if (ISBF) return __bfloat162float(((const __hip_bfloat16*)p)[i]);
  else      return ((const float*)p)[i];
}

// ---------- K1: fused blocks-gather/per-block-QKV (blocks 0..255) + weight repack ----------
template <bool ISBF>
__global__ void __launch_bounds__(256) k_prep2(
    const void* __restrict__ M,
    const void* __restrict__ Wqkv_blk,
    const void* __restrict__ bqkv_blk,
    const void* __restrict__ W1, const void* __restrict__ W2,
    const void* __restrict__ Wqkv_c, const void* __restrict__ Wo_c,
    const void* __restrict__ Wo_blk, const void* __restrict__ bo_blk,
    const void* __restrict__ bqkv_c, const void* __restrict__ bo_c,
    const void* __restrict__ g1, const void* __restrict__ be1,
    const void* __restrict__ b1, const void* __restrict__ b2,
    const void* __restrict__ g2, const void* __restrict__ be2,
    const void* __restrict__ sens_al,
    float* __restrict__ blocks, float* __restrict__ qkv_blk,
    float* __restrict__ params) {
  if (detect_bf16(M) != ISBF) return;
  if (blockIdx.x < 256) {
    int g = blockIdx.x * 256 + threadIdx.x;      // 65536 = 16 blocks * 4096 tokens
    int i = g >> 12, bt = g & 4095;
    int rb = i >> 2, cb = i & 3;
    float x[4];
    #pragma unroll
    for (int r = 0; r < 2; ++r)
      #pragma unroll
      for (int c = 0; c < 2; ++c)
        x[r*2+c] = ldf<ISBF>(M, bt*64 + (rb*2+r)*8 + cb*2 + c);
    float* bo = blocks + bt*64 + i*4;
    #pragma unroll
    for (int j = 0; j < 4; ++j) bo[j] = x[j];
    float* o = qkv_blk + (i*BT + bt) * 12;
    #pragma unroll
    for (int c = 0; c < 12; ++c) {
      float a = ldf<ISBF>(bqkv_blk, i*12 + c);
      #pragma unroll
      for (int j = 0; j < 4; ++j) a += ldf<ISBF>(Wqkv_blk, i*48 + c*4 + j) * x[j];
      o[c] = a;
    }
  } else {
    for (int o = (blockIdx.x - 256)*256 + threadIdx.x; o < P_TOTAL; o += 16*256) {
      float v;
      if      (o < 16384) { int j = o >> 8, h2 = o & 255; v = ldf<ISBF>(W1, h2*64 + j); }
      else if (o < 32768) { int q = o - 16384; int k = q >> 6, j = q & 63; v = ldf<ISBF>(W2, j*256 + k); }
      else if (o < 45056) { int q = o - 32768; int j = q / 192, c = q % 192; v = ldf<ISBF>(Wqkv_c, c*64 + j); }
      else if (o < 49152) { int q = o - 45056; int m = q >> 6, j = q & 63; v = ldf<ISBF>(Wo_c, j*64 + m); }
      else if (o < 49408) v = ldf<ISBF>(Wo_blk, o - 49152);
      else if (o < 49472) v = ldf<ISBF>(bo_blk, o - 49408);
      else if (o < 49664) v = ldf<ISBF>(bqkv_c, o - 49472);
      else if (o < 49728) v = ldf<ISBF>(bo_c,   o - 49664);
      else if (o < 49792) v = ldf<ISBF>(g1,     o - 49728);
      else if (o < 49856) v = ldf<ISBF>(be1,    o - 49792);
      else if (o < 50112) v = ldf<ISBF>(b1,     o - 49856);
      else if (o < 50176) v = ldf<ISBF>(b2,     o - 50112);
      else if (o < 50240) v = ldf<ISBF>(g2,     o - 50176);
      else if (o < 50304) v = ldf<ISBF>(be2,    o - 50240);
      else                v = ldf<ISBF>(sens_al, o - 50304);
      params[o] = v;
    }
  }
}

// ---------- K2: per-block attention, LDS-staged K/V, 8-wave key-split, 2 q/thread ----------
__global__ void __launch_bounds__(512) k_blk_part(
    const float* __restrict__ qkv_blk,
    const float* __restrict__ params,
    float* __restrict__ all_blocks) {
  __shared__ float4 kv4[3072];       // 48 KB: the (i,b) slab [1024 rows][12 floats]
  __shared__ float red[128*49];      // stride 49 (odd -> conflict-free)
  float* kv = (float*)kv4;
  int bid = blockIdx.x;              // grid 512 = 16i * 4b * 8qt
  int qt = bid & 7, b = (bid >> 3) & 3, i = bid >> 5;
  int tid = threadIdx.x;
  int wv = __builtin_amdgcn_readfirstlane(tid) >> 6;
  int ql = tid & 63;
  const float4* slab = (const float4*)(qkv_blk + (size_t)(i*BT + b*TT) * 12);
  #pragma unroll
  for (int s = 0; s < 6; ++s) kv4[tid + s*512] = slab[tid + s*512];
  __syncthreads();
  int qa = qt*128 + ql, qb = qa + 64;
  const float* qra = kv + qa*12;
  const float* qrb = kv + qb*12;
  const float S2 = 0.70710678f;      // 1/sqrt(Dh=2)
  float qa00 = qra[0]*S2, qa01 = qra[1]*S2, qa10 = qra[2]*S2, qa11 = qra[3]*S2;
  float qb00 = qrb[0]*S2, qb01 = qrb[1]*S2, qb10 = qrb[2]*S2, qb11 = qrb[3]*S2;
  float la0=0.f, la1=0.f, aa00=0.f, aa01=0.f, aa10=0.f, aa11=0.f;
  float lb0=0.f, lb1=0.f, ab00=0.f, ab01=0.f, ab10=0.f, ab11=0.f;
  int kbeg = wv*128;
  #pragma unroll 4
  for (int k = kbeg; k < kbeg + 128; ++k) {
    const float* kr = kv + k*12 + 4;      // LDS broadcast
    float k0=kr[0], k1=kr[1], k2=kr[2], k3=kr[3];
    float v0=kr[4], v1=kr[5], v2=kr[6], v3=kr[7];
    float pa0 = __expf(qa00*k0 + qa01*k1);
    float pa1 = __expf(qa10*k2 + qa11*k3);
    float pb0 = __expf(qb00*k0 + qb01*k1);
    float pb1 = __expf(qb10*k2 + qb11*k3);
    la0 += pa0; aa00 += pa0*v0; aa01 += pa0*v1;
    la1 += pa1; aa10 += pa1*v2; aa11 += pa1*v3;
    lb0 += pb0; ab00 += pb0*v0; ab01 += pb0*v1;
    lb1 += pb1; ab10 += pb1*v2; ab11 += pb1*v3;
  }
  float* ra = red + ql*49 + wv*6;
  ra[0]=la0; ra[1]=la1; ra[2]=aa00; ra[3]=aa01; ra[4]=aa10; ra[5]=aa11;
  float* rb = red + (ql+64)*49 + wv*6;
  rb[0]=lb0; rb[1]=lb1; rb[2]=ab00; rb[3]=ab01; rb[4]=ab10; rb[5]=ab11;
  __syncthreads();
  if (tid < 128) {
    float s[6] = {0.f,0.f,0.f,0.f,0.f,0.f};
    #pragma unroll
    for (int w = 0; w < 8; ++w) {
      const float* p = red + tid*49 + w*6;
      #pragma unroll
      for (int c = 0; c < 6; ++c) s[c] += p[c];
    }
    float r0 = rcpf(s[0]), r1 = rcpf(s[1]);
    float o[4] = { s[2]*r0, s[3]*r0, s[4]*r1, s[5]*r1 };
    int q2 = qt*128 + tid;
    const float* pWo = params + P_WOBLK + i*16;
    float* outp = all_blocks + (size_t)(b*TT + q2)*64 + i*4;
    #pragma unroll
    for (int j = 0; j < 4; ++j) {
      float a = params[P_BOBLK + i*4 + j];
      #pragma unroll
      for (int m2 = 0; m2 < 4; ++m2) a += pWo[j*4 + m2] * o[m2];
      outp[j] = a;
    }
  }
}

// ---------- K3: cross QKV projection, LDS-staged transposed weights ----------
__global__ void __launch_bounds__(256) k_qkv_c2(
    const float* __restrict__ all_blocks,
    const float* __restrict__ params,
    float* __restrict__ qkv_c) {
  __shared__ float w[12288];         // WqkvcT [64 j][192 c], 48 KB
  __shared__ float xs[256];
  int tid = threadIdx.x;
  int t0 = blockIdx.x * 4;           // grid 1024, wave per token
  {
    const float4* src = (const float4*)(params + P_WQCT);
    float4* dst = (float4*)w;
    #pragma unroll
    for (int i = tid; i < 3072; i += 256) dst[i] = src[i];
  }
  xs[tid] = all_blocks[t0*64 + tid];
  __syncthreads();
  int tt = tid >> 6, lane = tid & 63;
  int t = t0 + tt;
  const float* x = xs + tt*64;
  float a0 = params[P_BQC + lane];
  float a1 = params[P_BQC + 64 + lane];
  float a2 = params[P_BQC + 128 + lane];
  #pragma unroll 8
  for (int j = 0; j < 64; ++j) {
    const float* r = w + j*192;
    float xj = x[j];                           // LDS broadcast
    a0 += r[lane]       * xj;                  // stride-1 LDS, conflict-free
    a1 += r[64 + lane]  * xj;
    a2 += r[128 + lane] * xj;
  }
  float* o = qkv_c + (size_t)t*192;
  o[lane] = a0; o[64 + lane] = a1; o[128 + lane] = a2;
}

// ---------- K4: cross attention + fused recv, LDS K/V slab, 8-wave key-split,
//             2 queries/lane (halves uniform-LDS traffic vs 1 q/lane) ----------
__global__ void __launch_bounds__(512) k_cross7(
    const float* __restrict__ qkv_c,
    float* __restrict__ acc_c,
    float* __restrict__ recv_part) {
  // LDS arena (74.5 KB):
  //   K   : kv[0      .. 8192)   [k][8]
  //   V   : kv[8192   .. 16384)  [k][8]   (dead after main loop)
  //   red : kv[8192   .. 17536)  [128 q][73]  (overlays V + 4.5 KB)
  //   qbuf: kv[17536  .. 19072)  [128 q][12]  (8 scaled q, invl at +8)
  __shared__ __align__(16) float kv[19072];
  int bid = blockIdx.x;              // grid 256 = 4b * 8h * 8qt
  int qt = bid & 7, h = (bid >> 3) & 7, b = bid >> 6;
  int tid = threadIdx.x;
  int wv = __builtin_amdgcn_readfirstlane(tid) >> 6;
  int ql = tid & 63;
  int h8 = h*8;
  const float* base = qkv_c + (size_t)b*TT*192;
  // stage K and V slabs, coalesced float4
  #pragma unroll
  for (int r = tid; r < 1024; r += 512) {
    const float4* kp = (const float4*)(base + (size_t)r*192 + 64 + h8);
    const float4* vp = (const float4*)(base + (size_t)r*192 + 128 + h8);
    float4 k0 = kp[0], k1 = kp[1], v0 = vp[0], v1 = vp[1];
    float4* kd = (float4*)(kv + r*8);        kd[0] = k0; kd[1] = k1;
    float4* vd = (float4*)(kv + 8192 + r*8); vd[0] = v0; vd[1] = v1;
  }
  int qa = qt*128 + ql, qb = qa + 64;
  const float SC = 0.35355339f;      // 1/sqrt(8)
  float4 qa0, qa1, qb0, qb1;
  {
    const float4* pa = (const float4*)(base + (size_t)qa*192 + h8);
    const float4* pb = (const float4*)(base + (size_t)qb*192 + h8);
    qa0 = pa[0]; qa1 = pa[1]; qb0 = pb[0]; qb1 = pb[1];
    qa0.x*=SC; qa0.y*=SC; qa0.z*=SC; qa0.w*=SC;
    qa1.x*=SC; qa1.y*=SC; qa1.z*=SC; qa1.w*=SC;
    qb0.x*=SC; qb0.y*=SC; qb0.z*=SC; qb0.w*=SC;
    qb1.x*=SC; qb1.y*=SC; qb1.z*=SC; qb1.w*=SC;
  }
  __syncthreads();
  float la = 0.f, lb = 0.f, aca[8], acb[8];
  #pragma unroll
  for (int c = 0; c < 8; ++c) { aca[c] = 0.f; acb[c] = 0.f; }
  int kbeg = wv*128;
  #pragma unroll 2
  for (int k = kbeg; k < kbeg + 128; ++k) {
    const float4* kr4 = (const float4*)(kv + k*8);          // uniform -> broadcast
    const float4* vr4 = (const float4*)(kv + 8192 + k*8);
    float4 k0 = kr4[0], k1 = kr4[1];
    float4 v0 = vr4[0], v1 = vr4[1];
    float sa = qa0.x*k0.x + qa0.y*k0.y + qa0.z*k0.z + qa0.w*k0.w
             + qa1.x*k1.x + qa1.y*k1.y + qa1.z*k1.z + qa1.w*k1.w;
    float sb = qb0.x*k0.x + qb0.y*k0.y + qb0.z*k0.z + qb0.w*k0.w
             + qb1.x*k1.x + qb1.y*k1.y + qb1.z*k1.z + qb1.w*k1.w;
    float pa = __expf(sa);
    float pb = __expf(sb);
    la += pa; lb += pb;
    aca[0] += pa*v0.x; aca[1] += pa*v0.y; aca[2] += pa*v0.z; aca[3] += pa*v0.w;
    aca[4] += pa*v1.x; aca[5] += pa*v1.y; aca[6] += pa*v1.z; aca[7] += pa*v1.w;
    acb[0] += pb*v0.x; acb[1] += pb*v0.y; acb[2] += pb*v0.z; acb[3] += pb*v0.w;
    acb[4] += pb*v1.x; acb[5] += pb*v1.y; acb[6] += pb*v1.z; acb[7] += pb*v1.w;
  }
  __syncthreads();                   // V reads done; red overlays V region
  float* red  = kv + 8192;           // [128 q][73]  (stride 73, conflict-free)
  float* qbuf = kv + 17536;          // [128 q][12]
  {
    float* ra = red + ql*73 + wv*9;
    ra[0] = la;
    #pragma unroll
    for (int c = 0; c < 8; ++c) ra[1+c] = aca[c];
    float* rb = red + (ql+64)*73 + wv*9;
    rb[0] = lb;
    #pragma unroll
    for (int c = 0; c < 8; ++c) rb[1+c] = acb[c];
    if (wv == 0) {                   // wave 0's regs hold scaled q for all 128 queries
      float4* qd = (float4*)(qbuf + ql*12);
      qd[0] = qa0; qd[1] = qa1;
      float4* qd2 = (float4*)(qbuf + (ql+64)*12);
      qd2[0] = qb0; qd2[1] = qb1;
    }
  }
  __syncthreads();
  if (tid < 128) {
    float ls = 0.f, as[8];
    #pragma unroll
    for (int c = 0; c < 8; ++c) as[c] = 0.f;
    #pragma unroll
    for (int w = 0; w < 8; ++w) {
      const float* p = red + tid*73 + w*9;
      ls += p[0];
      #pragma unroll
      for (int c = 0; c < 8; ++c) as[c] += p[1+c];
    }
    float invl = rcpf(ls);
    int q2 = qt*128 + tid;
    int idx = (b*8 + h)*TT + q2;
    float4 o0 = { as[0]*invl, as[1]*invl, as[2]*invl, as[3]*invl };
    float4 o1 = { as[4]*invl, as[5]*invl, as[6]*invl, as[7]*invl };
    float4* op = (float4*)(acc_c + (size_t)idx*8);
    op[0] = o0; op[1] = o1;          // normalized PV
    qbuf[tid*12 + 8] = invl;
  }
  __syncthreads();
  // recv pass: 4 keys/lane (K region intact in LDS); waves split by query half.
  // waves 0-3 handle queries 0..63, waves 4-7 handle 64..127 of this block.
  {
    int qh = wv >> 2, g = wv & 3;
    int p = g*64 + ql;               // 0..255; keys p, p+256, p+512, p+768
    float K0[8], K1[8], K2[8], K3[8];
    {
      const float4* a = (const float4*)(kv + p*8);
      const float4* b2 = (const float4*)(kv + (p+256)*8);
      const float4* c2 = (const float4*)(kv + (p+512)*8);
      const float4* d2 = (const float4*)(kv + (p+768)*8);
      float4 t0 = a[0],  t1 = a[1];
      float4 t2 = b2[0], t3 = b2[1];
      float4 t4 = c2[0], t5 = c2[1];
      float4 t6 = d2[0], t7 = d2[1];
      K0[0]=t0.x;K0[1]=t0.y;K0[2]=t0.z;K0[3]=t0.w;K0[4]=t1.x;K0[5]=t1.y;K0[6]=t1.z;K0[7]=t1.w;
      K1[0]=t2.x;K1[1]=t2.y;K1[2]=t2.z;K1[3]=t2.w;K1[4]=t3.x;K1[5]=t3.y;K1[6]=t3.z;K1[7]=t3.w;
      K2[0]=t4.x;K2[1]=t4.y;K2[2]=t4.z;K2[3]=t4.w;K2[4]=t5.x;K2[5]=t5.y;K2[6]=t5.z;K2[7]=t5.w;
      K3[0]=t6.x;K3[1]=t6.y;K3[2]=t6.z;K3[3]=t6.w;K3[4]=t7.x;K3[5]=t7.y;K3[6]=t7.z;K3[7]=t7.w;
    }
    float r0 = 0.f, r1 = 0.f, r2 = 0.f, r3 = 0.f;
    const float* qb0p = qbuf + qh*64*12;
    #pragma unroll 2
    for (int qq = 0; qq < 64; ++qq) {
      const float* qr = qb0p + qq*12;          // uniform -> LDS broadcast
      float4 q0 = *(const float4*)qr;
      float4 q1 = *(const float4*)(qr + 4);
      float invl = qr[8];
      float s0 = q0.x*K0[0]+q0.y*K0[1]+q0.z*K0[2]+q0.w*K0[3]
               + q1.x*K0[4]+q1.y*K0[5]+q1.z*K0[6]+q1.w*K0[7];
      float s1 = q0.x*K1[0]+q0.y*K1[1]+q0.z*K1[2]+q0.w*K1[3]
               + q1.x*K1[4]+q1.y*K1[5]+q1.z*K1[6]+q1.w*K1[7];
      float s2 = q0.x*K2[0]+q0.y*K2[1]+q0.z*K2[2]+q0.w*K2[3]
               + q1.x*K2[4]+q1.y*K2[5]+q1.z*K2[6]+q1.w*K2[7];
      float s3 = q0.x*K3[0]+q0.y*K3[1]+q0.z*K3[2]+q0.w*K3[3]
               + q1.x*K3[4]+q1.y*K3[5]+q1.z*K3[6]+q1.w*K3[7];
      r0 += __expf(s0) * invl;
      r1 += __expf(s1) * invl;
      r2 += __expf(s2) * invl;
      r3 += __expf(s3) * invl;
    }
    int src = h*16 + qt*2 + qh;      // 0..127, unique per (h,qt,query-half)
    recv_part[((size_t)(b*1024 + p      ))*128 + src] = r0;
    recv_part[((size_t)(b*1024 + p + 256))*128 + src] = r1;
    recv_part[((size_t)(b*1024 + p + 512))*128 + src] = r2;
    recv_part[((size_t)(b*1024 + p + 768))*128 + src] = r3;
  }
}

// ---------- K5: finalize-cross only (Wo_c^T projection, residual, LN1) ----------
__global__ void __launch_bounds__(256) k_fin(
    const float* __restrict__ all_blocks,
    const float* __restrict__ acc_c,
    const float* __restrict__ params,
    float* __restrict__ ln1) {
  __shared__ float pvs[4*64];
  int tt = threadIdx.x >> 6, j = threadIdx.x & 63;
  int t = blockIdx.x*4 + tt;         // grid 1024
  int b = t >> 10, tl = t & 1023;
  int h = j >> 3;
  int idx = (b*8 + h)*TT + tl;
  pvs[tt*64 + j] = acc_c[idx*8 + (j & 7)];
  __syncthreads();
  float a = params[P_BOC + j];
  const float* WoT = params + P_WOCT;          // [m][64]
  const float* p = pvs + tt*64;
  #pragma unroll 8
  for (int m = 0; m < 64; ++m) a += WoT[m*64 + j] * p[m];   // coalesced + broadcast
  float x = all_blocks[t*64 + j] + a;
  float s = x, s2 = x*x;
  #pragma unroll
  for (int off = 32; off; off >>= 1) { s += __shfl_xor(s, off); s2 += __shfl_xor(s2, off); }
  float mu  = s  * (1.f/64.f);
  float var = s2 * (1.f/64.f) - mu*mu;
  float y = (x - mu) * rsqrtf(var + 1e-5f) * params[P_G1 + j] + params[P_BE1 + j];
  ln1[t*64 + j] = y;
}

// ---------- K6: FFN + LN2 + recv-reduce + gate + un-blocking; LDS-staged W1T/W2T ----------
template <bool ISBF>
__global__ void __launch_bounds__(512) k_ffn_out2(
    const void* __restrict__ M,
    const float* __restrict__ ln1,
    const float* __restrict__ params,
    const float* __restrict__ blocks,
    const int* __restrict__ tok32,
    const float* __restrict__ recv_part,
    const void* __restrict__ sens_emb,
    void* __restrict__ out) {
  if (detect_bf16(M) != ISBF) return;
  __shared__ float w[16384];     // W1T, then re-staged as W2T (64 KB)
  __shared__ float ld2[512];     // [j][tok8]
  __shared__ float hbuf[2048];   // [tok8][256]
  int tid = threadIdx.x;
  int t0 = blockIdx.x * 8;       // grid 512, 8 tokens per block
  int wv = tid >> 6, lane = tid & 63;
  // recv reduce (wave per token), result kept in a register for phase 2
  float recv;
  {
    int t = t0 + wv, b = t >> 10, k = t & 1023;
    const float* rp = recv_part + ((size_t)(b*1024 + k))*128;
    float s = rp[lane] + rp[lane + 64];
    #pragma unroll
    for (int off = 32; off; off >>= 1) s += __shfl_xor(s, off);
    recv = s * (1.f/8192.f);     // /(H=8 * T=1024)
  }
  ld2[lane*8 + wv] = ln1[(t0 + wv)*64 + lane];
  {
    const float4* src = (const float4*)(params + P_W1T);
    float4* dst = (float4*)w;
    #pragma unroll
    for (int i = tid; i < 4096; i += 512) dst[i] = src[i];
  }
  __syncthreads();
  // phase 1: hidden = gelu(ln1 @ W1^T + b1); half-block g handles tokens g*4..g*4+3
  {
    int g = tid >> 8, u = tid & 255;
    float a0, a1, a2, a3;
    a0 = a1 = a2 = a3 = params[P_B1 + u];
    #pragma unroll 8
    for (int j = 0; j < 64; ++j) {
      float wj = w[j*256 + u];                     // stride-1 LDS
      float4 xj = *(const float4*)(ld2 + j*8 + g*4); // broadcast b128
      a0 += wj*xj.x; a1 += wj*xj.y; a2 += wj*xj.z; a3 += wj*xj.w;
    }
    float av[4] = {a0, a1, a2, a3};
    #pragma unroll
    for (int t2 = 0; t2 < 4; ++t2) {
      float v = av[t2];
      float u2 = 1.5957691f*v + 0.07135481f*v*v*v;   // tanh-GELU sigmoid form
      hbuf[(g*4 + t2)*256 + u] = v * rcpf(1.f + __expf(-u2));
    }
  }
  __syncthreads();
  // re-stage W2T over the same arena
  {
    const float4* src = (const float4*)(params + P_W2T);
    float4* dst = (float4*)w;
    #pragma unroll
    for (int i = tid; i < 4096; i += 512) dst[i] = src[i];
  }
  __syncthreads();
  // phase 2: y = hidden @ W2^T + b2 (wave per token); LN2; gate; un-block
  int j = lane;
  int t = t0 + wv, b = t >> 10;
  float y = params[P_B2 + j];
  const float* hb = hbuf + wv*256;
  #pragma unroll 8
  for (int k = 0; k < 256; ++k) y += w[k*64 + j] * hb[k];   // stride-1 LDS + broadcast
  float z = ld2[j*8 + wv] + y;
  float s = z, s2 = z*z;
  #pragma unroll
  for (int off = 32; off; off >>= 1) { s += __shfl_xor(s, off); s2 += __shfl_xor(s2, off); }
  float mu  = s  * (1.f/64.f);
  float var = s2 * (1.f/64.f) - mu*mu;
  float y2 = (z - mu) * rsqrtf(var + 1e-5f) * params[P_G2 + j] + params[P_BE2 + j];
  bool is64 = ((tok32[1] | tok32[3] | tok32[5] | tok32[7]) == 0);
  int tok = is64 ? tok32[t*2] : tok32[t];
  int i = j >> 2, e = j & 3;
  float sv = ldf<ISBF>(sens_emb, tok*16 + i) + recv * params[P_SAL + i];
  float sg = rcpf(1.f + __expf(-sv));
  float blk = blocks[t*64 + j];
  float nb = blk + (y2 - blk) * sg;
  int rb = i >> 2, cb = i & 3, r = e >> 1, c = e & 1;
  int oidx = t*64 + (rb*2 + r)*8 + cb*2 + c;
  if (ISBF) ((__hip_bfloat16*)out)[oidx] = __float2bfloat16(nb);
  else      ((float*)out)[oidx] = nb;
}

extern "C" void kernel_launch(void* const* d_in, const int* in_sizes, int n_in,
                              void* d_out, int out_size, void* d_ws, size_t ws_size,
                              hipStream_t stream) {
  const void* M        = d_in[0];
  const int*  tok      = (const int*)d_in[1];
  const void* Wqkv_blk = d_in[2];
  const void* bqkv_blk = d_in[3];
  const void* Wo_blk   = d_in[4];
  const void* bo_blk   = d_in[5];
  const void* Wqkv_c   = d_in[6];
  const void* bqkv_c   = d_in[7];
  const void* Wo_c     = d_in[8];
  const void* bo_c     = d_in[9];
  const void* W1       = d_in[10];
  const void* b1       = d_in[11];
  const void* W2       = d_in[12];
  const void* b2       = d_in[13];
  const void* g1       = d_in[14];
  const void* be1      = d_in[15];
  const void* g2i      = d_in[16];
  const void* be2      = d_in[17];
  const void* sens_emb = d_in[18];
  const void* sens_al  = d_in[19];

  float* ws = (float*)d_ws;
  float* blocks    = ws + OFF_BLOCKS;
  float* qkv_blk   = ws + OFF_QKVB;
  float* recv_part = ws + OFF_RECVP;   // aliases qkv_blk (dead after k_blk_part)
  float* all_blk   = ws + OFF_ALLB;
  float* qkv_c     = ws + OFF_QKVC;
  float* acc_c     = ws + OFF_ACCC;
  float* ln1       = ws + OFF_LN1;
  float* params    = ws + OFF_PARAMS;

  k_prep2<true ><<<272, 256, 0, stream>>>(M, Wqkv_blk, bqkv_blk, W1, W2, Wqkv_c, Wo_c,
                                          Wo_blk, bo_blk, bqkv_c, bo_c, g1, be1, b1, b2,
                                          g2i, be2, sens_al, blocks, qkv_blk, params);
  k_prep2<false><<<272, 256, 0, stream>>>(M, Wqkv_blk, bqkv_blk, W1, W2, Wqkv_c, Wo_c,
                                          Wo_blk, bo_blk, bqkv_c, bo_c, g1, be1, b1, b2,
                                          g2i, be2, sens_al, blocks, qkv_blk, params);
  k_blk_part<<<512, 512, 0, stream>>>(qkv_blk, params, all_blk);
  k_qkv_c2<<<1024, 256, 0, stream>>>(all_blk, params, qkv_c);
  k_cross7<<<256, 512, 0, stream>>>(qkv_c, acc_c, recv_part);
  k_fin<<<1024, 256, 0, stream>>>(all_blk, acc_c, params, ln1);
  k_ffn_out2<true ><<<512, 512, 0, stream>>>(M, ln1, params, blocks, tok, recv_part,
                                             sens_emb, (void*)d_out);
  k_ffn_out2<false><<<512, 512, 0, stream>>>(M, ln1, params, blocks, tok, recv_part,
                                             sens_emb, (void*)d_out);
}

// Round 2
// 207.014 us; speedup vs baseline: 1.0210x; 1.0077x over previous
//
#include <hip/hip_runtime.h>
#include <hip/hip_bf16.h>
#include <math.h>

// Problem constants (setup_inputs: B=4, T=1024)
#define BB 4
#define TT 1024
#define BT 4096

// Workspace layout (fp32 offsets in floats)
#define OFF_BLOCKS 0          // [BT][64]  blocks in [i*4+e] channel order
#define OFF_QKVB   262144     // [16][BT][12] per-block qkv (dead after k_blk_part)
#define OFF_RECVP  262144     // [B][1024 k][128 src] recv partials (aliases QKVB, 2 MB)
#define OFF_ALLB   1048576    // [BT][64]  per-block MHA output (all_blocks)
#define OFF_QKVC   1310720    // [BT][192] cross qkv
#define OFF_LC     2097152    // [B*8][T]  (unused; kept for layout stability)
#define OFF_ACCC   2129920    // [B*8][T][8] cross PV (normalized by l)
#define OFF_LN1    2396160    // [BT][64]  post-LN1 activations
#define OFF_PARAMS 2658304    // repacked fp32 weights (see P_* below)
#define WS_FLOATS  2708624

// Param sub-offsets (floats, relative to OFF_PARAMS)
#define P_W1T    0        // [64 j][256 h]
#define P_W2T    16384    // [256 k][64 j]
#define P_WQCT   32768    // [64 j][192 c]
#define P_WOCT   45056    // [64 m][64 j]
#define P_WOBLK  49152    // [16 i][4 j][4 m]
#define P_BOBLK  49408
#define P_BQC    49472
#define P_BOC    49664
#define P_G1     49728
#define P_BE1    49792
#define P_B1     49856
#define P_B2     50112
#define P_G2     50176
#define P_BE2    50240
#define P_SAL    50304
#define P_TOTAL  50320

__device__ inline float rcpf(float x) { return __builtin_amdgcn_rcpf(x); }

// ---------- in-block dtype detection (wave-uniform) ----------
__device__ inline bool detect_bf16(const void* M) {
  const unsigned short* h = (const unsigned short*)M;
  unsigned short v = h[threadIdx.x & 63];
  int e = (v >> 7) & 0xff;
  unsigned long long m = __ballot((e >= 90) && (e <= 141));
  return __popcll(m) >= 58;
}

template <bool ISBF>
__device__ inline float ldf(const void* p, int i) {
  if (ISBF) return __bfloat162float(((const __hip_bfloat16*)p)[i]);
  else      return ((const float*)p)[i];
}

// ---------- K1: fused blocks-gather/per-block-QKV (blocks 0..255) + weight repack ----------
template <bool ISBF>
__global__ void __launch_bounds__(256) k_prep2(
    const void* __restrict__ M,
    const void* __restrict__ Wqkv_blk,
    const void* __restrict__ bqkv_blk,
    const void* __restrict__ W1, const void* __restrict__ W2,
    const void* __restrict__ Wqkv_c, const void* __restrict__ Wo_c,
    const void* __restrict__ Wo_blk, const void* __restrict__ bo_blk,
    const void* __restrict__ bqkv_c, const void* __restrict__ bo_c,
    const void* __restrict__ g1, const void* __restrict__ be1,
    const void* __restrict__ b1, const void* __restrict__ b2,
    const void* __restrict__ g2, const void* __restrict__ be2,
    const void* __restrict__ sens_al,
    float* __restrict__ blocks, float* __restrict__ qkv_blk,
    float* __restrict__ params) {
  if (detect_bf16(M) != ISBF) return;
  if (blockIdx.x < 256) {
    int g = blockIdx.x * 256 + threadIdx.x;      // 65536 = 16 blocks * 4096 tokens
    int i = g >> 12, bt = g & 4095;
    int rb = i >> 2, cb = i & 3;
    float x[4];
    #pragma unroll
    for (int r = 0; r < 2; ++r)
      #pragma unroll
      for (int c = 0; c < 2; ++c)
        x[r*2+c] = ldf<ISBF>(M, bt*64 + (rb*2+r)*8 + cb*2 + c);
    float* bo = blocks + bt*64 + i*4;
    #pragma unroll
    for (int j = 0; j < 4; ++j) bo[j] = x[j];
    float* o = qkv_blk + (i*BT + bt) * 12;
    #pragma unroll
    for (int c = 0; c < 12; ++c) {
      float a = ldf<ISBF>(bqkv_blk, i*12 + c);
      #pragma unroll
      for (int j = 0; j < 4; ++j) a += ldf<ISBF>(Wqkv_blk, i*48 + c*4 + j) * x[j];
      o[c] = a;
    }
  } else {
    for (int o = (blockIdx.x - 256)*256 + threadIdx.x; o < P_TOTAL; o += 16*256) {
      float v;
      if      (o < 16384) { int j = o >> 8, h2 = o & 255; v = ldf<ISBF>(W1, h2*64 + j); }
      else if (o < 32768) { int q = o - 16384; int k = q >> 6, j = q & 63; v = ldf<ISBF>(W2, j*256 + k); }
      else if (o < 45056) { int q = o - 32768; int j = q / 192, c = q % 192; v = ldf<ISBF>(Wqkv_c, c*64 + j); }
      else if (o < 49152) { int q = o - 45056; int m = q >> 6, j = q & 63; v = ldf<ISBF>(Wo_c, j*64 + m); }
      else if (o < 49408) v = ldf<ISBF>(Wo_blk, o - 49152);
      else if (o < 49472) v = ldf<ISBF>(bo_blk, o - 49408);
      else if (o < 49664) v = ldf<ISBF>(bqkv_c, o - 49472);
      else if (o < 49728) v = ldf<ISBF>(bo_c,   o - 49664);
      else if (o < 49792) v = ldf<ISBF>(g1,     o - 49728);
      else if (o < 49856) v = ldf<ISBF>(be1,    o - 49792);
      else if (o < 50112) v = ldf<ISBF>(b1,     o - 49856);
      else if (o < 50176) v = ldf<ISBF>(b2,     o - 50112);
      else if (o < 50240) v = ldf<ISBF>(g2,     o - 50176);
      else if (o < 50304) v = ldf<ISBF>(be2,    o - 50240);
      else                v = ldf<ISBF>(sens_al, o - 50304);
      params[o] = v;
    }
  }
}

// ---------- K2: per-block attention, LDS-staged K/V, 8-wave key-split, 2 q/thread ----------
__global__ void __launch_bounds__(512) k_blk_part(
    const float* __restrict__ qkv_blk,
    const float* __restrict__ params,
    float* __restrict__ all_blocks) {
  __shared__ float4 kv4[3072];       // 48 KB: the (i,b) slab [1024 rows][12 floats]
  __shared__ float red[128*49];      // stride 49 (odd -> conflict-free)
  float* kv = (float*)kv4;
  int bid = blockIdx.x;              // grid 512 = 16i * 4b * 8qt
  int qt = bid & 7, b = (bid >> 3) & 3, i = bid >> 5;
  int tid = threadIdx.x;
  int wv = __builtin_amdgcn_readfirstlane(tid) >> 6;
  int ql = tid & 63;
  const float4* slab = (const float4*)(qkv_blk + (size_t)(i*BT + b*TT) * 12);
  #pragma unroll
  for (int s = 0; s < 6; ++s) kv4[tid + s*512] = slab[tid + s*512];
  __syncthreads();
  int qa = qt*128 + ql, qb = qa + 64;
  const float* qra = kv + qa*12;
  const float* qrb = kv + qb*12;
  const float S2 = 0.70710678f;      // 1/sqrt(Dh=2)
  float qa00 = qra[0]*S2, qa01 = qra[1]*S2, qa10 = qra[2]*S2, qa11 = qra[3]*S2;
  float qb00 = qrb[0]*S2, qb01 = qrb[1]*S2, qb10 = qrb[2]*S2, qb11 = qrb[3]*S2;
  float la0=0.f, la1=0.f, aa00=0.f, aa01=0.f, aa10=0.f, aa11=0.f;
  float lb0=0.f, lb1=0.f, ab00=0.f, ab01=0.f, ab10=0.f, ab11=0.f;
  int kbeg = wv*128;
  #pragma unroll 4
  for (int k = kbeg; k < kbeg + 128; ++k) {
    const float* kr = kv + k*12 + 4;      // LDS broadcast
    float k0=kr[0], k1=kr[1], k2=kr[2], k3=kr[3];
    float v0=kr[4], v1=kr[5], v2=kr[6], v3=kr[7];
    float pa0 = __expf(qa00*k0 + qa01*k1);
    float pa1 = __expf(qa10*k2 + qa11*k3);
    float pb0 = __expf(qb00*k0 + qb01*k1);
    float pb1 = __expf(qb10*k2 + qb11*k3);
    la0 += pa0; aa00 += pa0*v0; aa01 += pa0*v1;
    la1 += pa1; aa10 += pa1*v2; aa11 += pa1*v3;
    lb0 += pb0; ab00 += pb0*v0; ab01 += pb0*v1;
    lb1 += pb1; ab10 += pb1*v2; ab11 += pb1*v3;
  }
  float* ra = red + ql*49 + wv*6;
  ra[0]=la0; ra[1]=la1; ra[2]=aa00; ra[3]=aa01; ra[4]=aa10; ra[5]=aa11;
  float* rb = red + (ql+64)*49 + wv*6;
  rb[0]=lb0; rb[1]=lb1; rb[2]=ab00; rb[3]=ab01; rb[4]=ab10; rb[5]=ab11;
  __syncthreads();
  if (tid < 128) {
    float s[6] = {0.f,0.f,0.f,0.f,0.f,0.f};
    #pragma unroll
    for (int w = 0; w < 8; ++w) {
      const float* p = red + tid*49 + w*6;
      #pragma unroll
      for (int c = 0; c < 6; ++c) s[c] += p[c];
    }
    float r0 = rcpf(s[0]), r1 = rcpf(s[1]);
    float o[4] = { s[2]*r0, s[3]*r0, s[4]*r1, s[5]*r1 };
    int q2 = qt*128 + tid;
    const float* pWo = params + P_WOBLK + i*16;
    float* outp = all_blocks + (size_t)(b*TT + q2)*64 + i*4;
    #pragma unroll
    for (int j = 0; j < 4; ++j) {
      float a = params[P_BOBLK + i*4 + j];
      #pragma unroll
      for (int m2 = 0; m2 < 4; ++m2) a += pWo[j*4 + m2] * o[m2];
      outp[j] = a;
    }
  }
}

// ---------- K3: cross QKV projection, LDS-staged transposed weights ----------
__global__ void __launch_bounds__(256) k_qkv_c2(
    const float* __restrict__ all_blocks,
    const float* __restrict__ params,
    float* __restrict__ qkv_c) {
  __shared__ float w[12288];         // WqkvcT [64 j][192 c], 48 KB
  __shared__ float xs[256];
  int tid = threadIdx.x;
  int t0 = blockIdx.x * 4;           // grid 1024, wave per token
  {
    const float4* src = (const float4*)(params + P_WQCT);
    float4* dst = (float4*)w;
    #pragma unroll
    for (int i = tid; i < 3072; i += 256) dst[i] = src[i];
  }
  xs[tid] = all_blocks[t0*64 + tid];
  __syncthreads();
  int tt = tid >> 6, lane = tid & 63;
  int t = t0 + tt;
  const float* x = xs + tt*64;
  float a0 = params[P_BQC + lane];
  float a1 = params[P_BQC + 64 + lane];
  float a2 = params[P_BQC + 128 + lane];
  #pragma unroll 8
  for (int j = 0; j < 64; ++j) {
    const float* r = w + j*192;
    float xj = x[j];                           // LDS broadcast
    a0 += r[lane]       * xj;                  // stride-1 LDS, conflict-free
    a1 += r[64 + lane]  * xj;
    a2 += r[128 + lane] * xj;
  }
  float* o = qkv_c + (size_t)t*192;
  o[lane] = a0; o[64 + lane] = a1; o[128 + lane] = a2;
}

// ---------- K4: cross attention + fused recv; 1024 threads (16 waves),
//             16-way key-split, 2 queries/lane. Grid 256 = 1 block/CU,
//             16 waves/CU restores latency hiding lost at 8 waves. ----------
__global__ void __launch_bounds__(1024) k_cross8(
    const float* __restrict__ qkv_c,
    float* __restrict__ acc_c,
    float* __restrict__ recv_part) {
  // LDS arena (110.5 KB):
  //   K   : kv[0      .. 8192)    [k][8]
  //   V   : kv[8192   .. 16384)   [k][8]   (dead after main loop)
  //   red : kv[8192   .. 26752)   [128 q][145]  (overlays V; stride 145 odd)
  //   qbuf: kv[26752  .. 28288)   [128 q][12]   (8 scaled q, invl at +8)
  __shared__ __align__(16) float kv[28288];
  int bid = blockIdx.x;              // grid 256 = 4b * 8h * 8qt
  int qt = bid & 7, h = (bid >> 3) & 7, b = bid >> 6;
  int tid = threadIdx.x;
  int wv = __builtin_amdgcn_readfirstlane(tid) >> 6;   // 0..15
  int ql = tid & 63;
  int h8 = h*8;
  const float* base = qkv_c + (size_t)b*TT*192;
  // stage K and V slabs, coalesced float4 (1024 threads, 1 row each)
  {
    int r = tid;
    const float4* kp = (const float4*)(base + (size_t)r*192 + 64 + h8);
    const float4* vp = (const float4*)(base + (size_t)r*192 + 128 + h8);
    float4 k0 = kp[0], k1 = kp[1], v0 = vp[0], v1 = vp[1];
    float4* kd = (float4*)(kv + r*8);        kd[0] = k0; kd[1] = k1;
    float4* vd = (float4*)(kv + 8192 + r*8); vd[0] = v0; vd[1] = v1;
  }
  int qa = qt*128 + ql, qb = qa + 64;
  const float SC = 0.35355339f;      // 1/sqrt(8)
  float4 qa0, qa1, qb0, qb1;
  {
    const float4* pa = (const float4*)(base + (size_t)qa*192 + h8);
    const float4* pb = (const float4*)(base + (size_t)qb*192 + h8);
    qa0 = pa[0]; qa1 = pa[1]; qb0 = pb[0]; qb1 = pb[1];
    qa0.x*=SC; qa0.y*=SC; qa0.z*=SC; qa0.w*=SC;
    qa1.x*=SC; qa1.y*=SC; qa1.z*=SC; qa1.w*=SC;
    qb0.x*=SC; qb0.y*=SC; qb0.z*=SC; qb0.w*=SC;
    qb1.x*=SC; qb1.y*=SC; qb1.z*=SC; qb1.w*=SC;
  }
  __syncthreads();
  float la = 0.f, lb = 0.f, aca[8], acb[8];
  #pragma unroll
  for (int c = 0; c < 8; ++c) { aca[c] = 0.f; acb[c] = 0.f; }
  int kbeg = wv*64;
  #pragma unroll 2
  for (int k = kbeg; k < kbeg + 64; ++k) {
    const float4* kr4 = (const float4*)(kv + k*8);          // uniform -> broadcast
    const float4* vr4 = (const float4*)(kv + 8192 + k*8);
    float4 k0 = kr4[0], k1 = kr4[1];
    float4 v0 = vr4[0], v1 = vr4[1];
    float sa = qa0.x*k0.x + qa0.y*k0.y + qa0.z*k0.z + qa0.w*k0.w
             + qa1.x*k1.x + qa1.y*k1.y + qa1.z*k1.z + qa1.w*k1.w;
    float sb = qb0.x*k0.x + qb0.y*k0.y + qb0.z*k0.z + qb0.w*k0.w
             + qb1.x*k1.x + qb1.y*k1.y + qb1.z*k1.z + qb1.w*k1.w;
    float pa = __expf(sa);
    float pb = __expf(sb);
    la += pa; lb += pb;
    aca[0] += pa*v0.x; aca[1] += pa*v0.y; aca[2] += pa*v0.z; aca[3] += pa*v0.w;
    aca[4] += pa*v1.x; aca[5] += pa*v1.y; aca[6] += pa*v1.z; aca[7] += pa*v1.w;
    acb[0] += pb*v0.x; acb[1] += pb*v0.y; acb[2] += pb*v0.z; acb[3] += pb*v0.w;
    acb[4] += pb*v1.x; acb[5] += pb*v1.y; acb[6] += pb*v1.z; acb[7] += pb*v1.w;
  }
  __syncthreads();                   // V reads done; red overlays V region
  float* red  = kv + 8192;           // [128 q][145]  (stride 145, conflict-free)
  float* qbuf = kv + 26752;          // [128 q][12]
  {
    float* ra = red + ql*145 + wv*9;
    ra[0] = la;
    #pragma unroll
    for (int c = 0; c < 8; ++c) ra[1+c] = aca[c];
    float* rb = red + (ql+64)*145 + wv*9;
    rb[0] = lb;
    #pragma unroll
    for (int c = 0; c < 8; ++c) rb[1+c] = acb[c];
    if (wv == 0) {                   // wave 0's regs hold scaled q for all 128 queries
      float4* qd = (float4*)(qbuf + ql*12);
      qd[0] = qa0; qd[1] = qa1;
      float4* qd2 = (float4*)(qbuf + (ql+64)*12);
      qd2[0] = qb0; qd2[1] = qb1;
    }
  }
  __syncthreads();
  if (tid < 128) {
    float ls = 0.f, as[8];
    #pragma unroll
    for (int c = 0; c < 8; ++c) as[c] = 0.f;
    #pragma unroll
    for (int w = 0; w < 16; ++w) {
      const float* p = red + tid*145 + w*9;
      ls += p[0];
      #pragma unroll
      for (int c = 0; c < 8; ++c) as[c] += p[1+c];
    }
    float invl = rcpf(ls);
    int q2 = qt*128 + tid;
    int idx = (b*8 + h)*TT + q2;
    float4 o0 = { as[0]*invl, as[1]*invl, as[2]*invl, as[3]*invl };
    float4 o1 = { as[4]*invl, as[5]*invl, as[6]*invl, as[7]*invl };
    float4* op = (float4*)(acc_c + (size_t)idx*8);
    op[0] = o0; op[1] = o1;          // normalized PV
    qbuf[tid*12 + 8] = invl;
  }
  __syncthreads();
  // recv pass: 2 keys/lane (K region intact in LDS); waves split by query half.
  // waves 0-7 handle queries 0..63, waves 8-15 handle 64..127 of this block.
  {
    int qh = wv >> 3, g = wv & 7;
    int p = g*64 + ql;               // 0..511; keys p, p+512
    float K0[8], K1[8];
    {
      const float4* a  = (const float4*)(kv + p*8);
      const float4* b2 = (const float4*)(kv + (p+512)*8);
      float4 t0 = a[0],  t1 = a[1];
      float4 t2 = b2[0], t3 = b2[1];
      K0[0]=t0.x;K0[1]=t0.y;K0[2]=t0.z;K0[3]=t0.w;K0[4]=t1.x;K0[5]=t1.y;K0[6]=t1.z;K0[7]=t1.w;
      K1[0]=t2.x;K1[1]=t2.y;K1[2]=t2.z;K1[3]=t2.w;K1[4]=t3.x;K1[5]=t3.y;K1[6]=t3.z;K1[7]=t3.w;
    }
    float r0 = 0.f, r1 = 0.f;
    const float* qb0p = qbuf + qh*64*12;
    #pragma unroll 4
    for (int qq = 0; qq < 64; ++qq) {
      const float* qr = qb0p + qq*12;          // uniform -> LDS broadcast
      float4 q0 = *(const float4*)qr;
      float4 q1 = *(const float4*)(qr + 4);
      float invl = qr[8];
      float s0 = q0.x*K0[0]+q0.y*K0[1]+q0.z*K0[2]+q0.w*K0[3]
               + q1.x*K0[4]+q1.y*K0[5]+q1.z*K0[6]+q1.w*K0[7];
      float s1 = q0.x*K1[0]+q0.y*K1[1]+q0.z*K1[2]+q0.w*K1[3]
               + q1.x*K1[4]+q1.y*K1[5]+q1.z*K1[6]+q1.w*K1[7];
      r0 += __expf(s0) * invl;
      r1 += __expf(s1) * invl;
    }
    int src = h*16 + qt*2 + qh;      // 0..127, unique per (h,qt,query-half)
    recv_part[((size_t)(b*1024 + p      ))*128 + src] = r0;
    recv_part[((size_t)(b*1024 + p + 512))*128 + src] = r1;
  }
}

// ---------- K5: finalize-cross only (Wo_c^T projection, residual, LN1) ----------
__global__ void __launch_bounds__(256) k_fin(
    const float* __restrict__ all_blocks,
    const float* __restrict__ acc_c,
    const float* __restrict__ params,
    float* __restrict__ ln1) {
  __shared__ float pvs[4*64];
  int tt = threadIdx.x >> 6, j = threadIdx.x & 63;
  int t = blockIdx.x*4 + tt;         // grid 1024
  int b = t >> 10, tl = t & 1023;
  int h = j >> 3;
  int idx = (b*8 + h)*TT + tl;
  pvs[tt*64 + j] = acc_c[idx*8 + (j & 7)];
  __syncthreads();
  float a = params[P_BOC + j];
  const float* WoT = params + P_WOCT;          // [m][64]
  const float* p = pvs + tt*64;
  #pragma unroll 8
  for (int m = 0; m < 64; ++m) a += WoT[m*64 + j] * p[m];   // coalesced + broadcast
  float x = all_blocks[t*64 + j] + a;
  float s = x, s2 = x*x;
  #pragma unroll
  for (int off = 32; off; off >>= 1) { s += __shfl_xor(s, off); s2 += __shfl_xor(s2, off); }
  float mu  = s  * (1.f/64.f);
  float var = s2 * (1.f/64.f) - mu*mu;
  float y = (x - mu) * rsqrtf(var + 1e-5f) * params[P_G1 + j] + params[P_BE1 + j];
  ln1[t*64 + j] = y;
}

// ---------- K6: FFN + LN2 + recv-reduce + gate + un-blocking; LDS-staged W1T/W2T ----------
template <bool ISBF>
__global__ void __launch_bounds__(512) k_ffn_out2(
    const void* __restrict__ M,
    const float* __restrict__ ln1,
    const float* __restrict__ params,
    const float* __restrict__ blocks,
    const int* __restrict__ tok32,
    const float* __restrict__ recv_part,
    const void* __restrict__ sens_emb,
    void* __restrict__ out) {
  if (detect_bf16(M) != ISBF) return;
  __shared__ float w[16384];     // W1T, then re-staged as W2T (64 KB)
  __shared__ float ld2[512];     // [j][tok8]
  __shared__ float hbuf[2048];   // [tok8][256]
  int tid = threadIdx.x;
  int t0 = blockIdx.x * 8;       // grid 512, 8 tokens per block
  int wv = tid >> 6, lane = tid & 63;
  // recv reduce (wave per token), result kept in a register for phase 2
  float recv;
  {
    int t = t0 + wv, b = t >> 10, k = t & 1023;
    const float* rp = recv_part + ((size_t)(b*1024 + k))*128;
    float s = rp[lane] + rp[lane + 64];
    #pragma unroll
    for (int off = 32; off; off >>= 1) s += __shfl_xor(s, off);
    recv = s * (1.f/8192.f);     // /(H=8 * T=1024)
  }
  ld2[lane*8 + wv] = ln1[(t0 + wv)*64 + lane];
  {
    const float4* src = (const float4*)(params + P_W1T);
    float4* dst = (float4*)w;
    #pragma unroll
    for (int i = tid; i < 4096; i += 512) dst[i] = src[i];
  }
  __syncthreads();
  // phase 1: hidden = gelu(ln1 @ W1^T + b1); half-block g handles tokens g*4..g*4+3
  {
    int g = tid >> 8, u = tid & 255;
    float a0, a1, a2, a3;
    a0 = a1 = a2 = a3 = params[P_B1 + u];
    #pragma unroll 8
    for (int j = 0; j < 64; ++j) {
      float wj = w[j*256 + u];                     // stride-1 LDS
      float4 xj = *(const float4*)(ld2 + j*8 + g*4); // broadcast b128
      a0 += wj*xj.x; a1 += wj*xj.y; a2 += wj*xj.z; a3 += wj*xj.w;
    }
    float av[4] = {a0, a1, a2, a3};
    #pragma unroll
    for (int t2 = 0; t2 < 4; ++t2) {
      float v = av[t2];
      float u2 = 1.5957691f*v + 0.07135481f*v*v*v;   // tanh-GELU sigmoid form
      hbuf[(g*4 + t2)*256 + u] = v * rcpf(1.f + __expf(-u2));
    }
  }
  __syncthreads();
  // re-stage W2T over the same arena
  {
    const float4* src = (const float4*)(params + P_W2T);
    float4* dst = (float4*)w;
    #pragma unroll
    for (int i = tid; i < 4096; i += 512) dst[i] = src[i];
  }
  __syncthreads();
  // phase 2: y = hidden @ W2^T + b2 (wave per token); LN2; gate; un-block
  int j = lane;
  int t = t0 + wv, b = t >> 10;
  float y = params[P_B2 + j];
  const float* hb = hbuf + wv*256;
  #pragma unroll 8
  for (int k = 0; k < 256; ++k) y += w[k*64 + j] * hb[k];   // stride-1 LDS + broadcast
  float z = ld2[j*8 + wv] + y;
  float s = z, s2 = z*z;
  #pragma unroll
  for (int off = 32; off; off >>= 1) { s += __shfl_xor(s, off); s2 += __shfl_xor(s2, off); }
  float mu  = s  * (1.f/64.f);
  float var = s2 * (1.f/64.f) - mu*mu;
  float y2 = (z - mu) * rsqrtf(var + 1e-5f) * params[P_G2 + j] + params[P_BE2 + j];
  bool is64 = ((tok32[1] | tok32[3] | tok32[5] | tok32[7]) == 0);
  int tok = is64 ? tok32[t*2] : tok32[t];
  int i = j >> 2, e = j & 3;
  float sv = ldf<ISBF>(sens_emb, tok*16 + i) + recv * params[P_SAL + i];
  float sg = rcpf(1.f + __expf(-sv));
  float blk = blocks[t*64 + j];
  float nb = blk + (y2 - blk) * sg;
  int rb = i >> 2, cb = i & 3, r = e >> 1, c = e & 1;
  int oidx = t*64 + (rb*2 + r)*8 + cb*2 + c;
  if (ISBF) ((__hip_bfloat16*)out)[oidx] = __float2bfloat16(nb);
  else      ((float*)out)[oidx] = nb;
}

extern "C" void kernel_launch(void* const* d_in, const int* in_sizes, int n_in,
                              void* d_out, int out_size, void* d_ws, size_t ws_size,
                              hipStream_t stream) {
  const void* M        = d_in[0];
  const int*  tok      = (const int*)d_in[1];
  const void* Wqkv_blk = d_in[2];
  const void* bqkv_blk = d_in[3];
  const void* Wo_blk   = d_in[4];
  const void* bo_blk   = d_in[5];
  const void* Wqkv_c   = d_in[6];
  const void* bqkv_c   = d_in[7];
  const void* Wo_c     = d_in[8];
  const void* bo_c     = d_in[9];
  const void* W1       = d_in[10];
  const void* b1       = d_in[11];
  const void* W2       = d_in[12];
  const void* b2       = d_in[13];
  const void* g1       = d_in[14];
  const void* be1      = d_in[15];
  const void* g2i      = d_in[16];
  const void* be2      = d_in[17];
  const void* sens_emb = d_in[18];
  const void* sens_al  = d_in[19];

  float* ws = (float*)d_ws;
  float* blocks    = ws + OFF_BLOCKS;
  float* qkv_blk   = ws + OFF_QKVB;
  float* recv_part = ws + OFF_RECVP;   // aliases qkv_blk (dead after k_blk_part)
  float* all_blk   = ws + OFF_ALLB;
  float* qkv_c     = ws + OFF_QKVC;
  float* acc_c     = ws + OFF_ACCC;
  float* ln1       = ws + OFF_LN1;
  float* params    = ws + OFF_PARAMS;

  k_prep2<true ><<<272, 256, 0, stream>>>(M, Wqkv_blk, bqkv_blk, W1, W2, Wqkv_c, Wo_c,
                                          Wo_blk, bo_blk, bqkv_c, bo_c, g1, be1, b1, b2,
                                          g2i, be2, sens_al, blocks, qkv_blk, params);
  k_prep2<false><<<272, 256, 0, stream>>>(M, Wqkv_blk, bqkv_blk, W1, W2, Wqkv_c, Wo_c,
                                          Wo_blk, bo_blk, bqkv_c, bo_c, g1, be1, b1, b2,
                                          g2i, be2, sens_al, blocks, qkv_blk, params);
  k_blk_part<<<512, 512, 0, stream>>>(qkv_blk, params, all_blk);
  k_qkv_c2<<<1024, 256, 0, stream>>>(all_blk, params, qkv_c);
  k_cross8<<<256, 1024, 0, stream>>>(qkv_c, acc_c, recv_part);
  k_fin<<<1024, 256, 0, stream>>>(all_blk, acc_c, params, ln1);
  k_ffn_out2<true ><<<512, 512, 0, stream>>>(M, ln1, params, blocks, tok, recv_part,
                                             sens_emb, (void*)d_out);
  k_ffn_out2<false><<<512, 512, 0, stream>>>(M, ln1, params, blocks, tok, recv_part,
                                             sens_emb, (void*)d_out);
}

// Round 5
// 204.758 us; speedup vs baseline: 1.0323x; 1.0110x over previous
//
#include <hip/hip_runtime.h>
#include <hip/hip_bf16.h>
#include <math.h>

// Problem constants (setup_inputs: B=4, T=1024)
#define BB 4
#define TT 1024
#define BT 4096

// Workspace layout (fp32 offsets in floats)
#define OFF_BLOCKS 0          // [BT][64]  blocks in [i*4+e] channel order
#define OFF_QKVB   262144     // [16][BT][12] per-block qkv (dead after k_blk2)
#define OFF_RECVP  262144     // [B][1024 k][128 src] recv partials (aliases QKVB, 2 MB)
#define OFF_ALLB   1048576    // [BT][64]  per-block MHA output (all_blocks)
#define OFF_QKVC   1310720    // [BT][192] cross qkv
#define OFF_LC     2097152    // [B*8][T]  (unused; kept for layout stability)
#define OFF_ACCC   2129920    // [B*8][T][8] cross PV (normalized by l)
#define OFF_LN1    2396160    // [BT][64]  post-LN1 activations
#define OFF_PARAMS 2658304    // repacked fp32 weights (see P_* below)
#define WS_FLOATS  2708624

// Param sub-offsets (floats, relative to OFF_PARAMS)
#define P_W1T    0        // [64 j][256 h]
#define P_W2T    16384    // [256 k][64 j]
#define P_WQCT   32768    // [64 j][192 c]
#define P_WOCT   45056    // [64 m][64 j]
#define P_WOBLK  49152    // [16 i][4 j][4 m]
#define P_BOBLK  49408
#define P_BQC    49472
#define P_BOC    49664
#define P_G1     49728
#define P_BE1    49792
#define P_B1     49856
#define P_B2     50112
#define P_G2     50176
#define P_BE2    50240
#define P_SAL    50304
#define P_TOTAL  50320

__device__ inline float rcpf(float x) { return __builtin_amdgcn_rcpf(x); }

// ---------- f16 pack helpers ----------
typedef _Float16 h2 __attribute__((ext_vector_type(2)));
typedef __fp16   fh2 __attribute__((ext_vector_type(2)));   // cvt_pkrtz return type

__device__ inline uint pkh(float a, float b) {
#if __has_builtin(__builtin_amdgcn_cvt_pkrtz)
  fh2 r = __builtin_amdgcn_cvt_pkrtz(a, b);
  return __builtin_bit_cast(uint, r);
#else
  h2 r = { (_Float16)a, (_Float16)b };
  return __builtin_bit_cast(uint, r);
#endif
}
__device__ inline h2 toh2(uint u) { return __builtin_bit_cast(h2, u); }

__device__ inline float dot2h(h2 a, h2 b, float c) {
#if __has_builtin(__builtin_amdgcn_fdot2)
  return __builtin_amdgcn_fdot2(a, b, c, false);
#else
  return c + (float)a.x * (float)b.x + (float)a.y * (float)b.y;   // v_fma_mix
#endif
}

// ---------- in-block dtype detection (wave-uniform) ----------
__device__ inline bool detect_bf16(const void* M) {
  const unsigned short* h = (const unsigned short*)M;
  unsigned short v = h[threadIdx.x & 63];
  int e = (v >> 7) & 0xff;
  unsigned long long m = __ballot((e >= 90) && (e <= 141));
  return __popcll(m) >= 58;
}

template <bool ISBF>
__device__ inline float ldf(const void* p, int i) {
  if (ISBF) return __bfloat162float(((const __hip_bfloat16*)p)[i]);
  else      return ((const float*)p)[i];
}

// ---------- K1: fused blocks-gather/per-block-QKV (blocks 0..255) + weight repack ----------
template <bool ISBF>
__global__ void __launch_bounds__(256) k_prep2(
    const void* __restrict__ M,
    const void* __restrict__ Wqkv_blk,
    const void* __restrict__ bqkv_blk,
    const void* __restrict__ W1, const void* __restrict__ W2,
    const void* __restrict__ Wqkv_c, const void* __restrict__ Wo_c,
    const void* __restrict__ Wo_blk, const void* __restrict__ bo_blk,
    const void* __restrict__ bqkv_c, const void* __restrict__ bo_c,
    const void* __restrict__ g1, const void* __restrict__ be1,
    const void* __restrict__ b1, const void* __restrict__ b2,
    const void* __restrict__ g2, const void* __restrict__ be2,
    const void* __restrict__ sens_al,
    float* __restrict__ blocks, float* __restrict__ qkv_blk,
    float* __restrict__ params) {
  if (detect_bf16(M) != ISBF) return;
  if (blockIdx.x < 256) {
    int g = blockIdx.x * 256 + threadIdx.x;      // 65536 = 16 blocks * 4096 tokens
    int i = g >> 12, bt = g & 4095;
    int rb = i >> 2, cb = i & 3;
    float x[4];
    #pragma unroll
    for (int r = 0; r < 2; ++r)
      #pragma unroll
      for (int c = 0; c < 2; ++c)
        x[r*2+c] = ldf<ISBF>(M, bt*64 + (rb*2+r)*8 + cb*2 + c);
    float* bo = blocks + bt*64 + i*4;
    #pragma unroll
    for (int j = 0; j < 4; ++j) bo[j] = x[j];
    float* o = qkv_blk + (i*BT + bt) * 12;
    #pragma unroll
    for (int c = 0; c < 12; ++c) {
      float a = ldf<ISBF>(bqkv_blk, i*12 + c);
      #pragma unroll
      for (int j = 0; j < 4; ++j) a += ldf<ISBF>(Wqkv_blk, i*48 + c*4 + j) * x[j];
      o[c] = a;
    }
  } else {
    for (int o = (blockIdx.x - 256)*256 + threadIdx.x; o < P_TOTAL; o += 16*256) {
      float v;
      if      (o < 16384) { int j = o >> 8, h2_ = o & 255; v = ldf<ISBF>(W1, h2_*64 + j); }
      else if (o < 32768) { int q = o - 16384; int k = q >> 6, j = q & 63; v = ldf<ISBF>(W2, j*256 + k); }
      else if (o < 45056) { int q = o - 32768; int j = q / 192, c = q % 192; v = ldf<ISBF>(Wqkv_c, c*64 + j); }
      else if (o < 49152) { int q = o - 45056; int m = q >> 6, j = q & 63; v = ldf<ISBF>(Wo_c, j*64 + m); }
      else if (o < 49408) v = ldf<ISBF>(Wo_blk, o - 49152);
      else if (o < 49472) v = ldf<ISBF>(bo_blk, o - 49408);
      else if (o < 49664) v = ldf<ISBF>(bqkv_c, o - 49472);
      else if (o < 49728) v = ldf<ISBF>(bo_c,   o - 49664);
      else if (o < 49792) v = ldf<ISBF>(g1,     o - 49728);
      else if (o < 49856) v = ldf<ISBF>(be1,    o - 49792);
      else if (o < 50112) v = ldf<ISBF>(b1,     o - 49856);
      else if (o < 50176) v = ldf<ISBF>(b2,     o - 50112);
      else if (o < 50240) v = ldf<ISBF>(g2,     o - 50176);
      else if (o < 50304) v = ldf<ISBF>(be2,    o - 50240);
      else                v = ldf<ISBF>(sens_al, o - 50304);
      params[o] = v;
    }
  }
}

// ---------- K2: per-block attention; Q f32 + packed-f16 K/V in LDS (1 b128/key),
//             8-wave key-split, 2 q/thread, fdot2 + fma_mix consume packed data ----------
__global__ void __launch_bounds__(512) k_blk2(
    const float* __restrict__ qkv_blk,
    const float* __restrict__ params,
    float* __restrict__ all_blocks) {
  // LDS (56.5 KB): qf [1024][4] f32 | kvu [1024][4] u32 {k01,k23,v01,v23} f16 | red [128][49]
  __shared__ __align__(16) uint lds[14464];
  float* qf  = (float*)lds;
  uint*  kvu = lds + 4096;
  float* red = (float*)(lds + 8192);
  int bid = blockIdx.x;              // grid 512 = 16i * 4b * 8qt
  int qt = bid & 7, b = (bid >> 3) & 3, i = bid >> 5;
  int tid = threadIdx.x;
  int wv = __builtin_amdgcn_readfirstlane(tid) >> 6;
  int ql = tid & 63;
  const float* slab = qkv_blk + (size_t)(i*BT + b*TT) * 12;
  #pragma unroll
  for (int rr = 0; rr < 2; ++rr) {
    int r = tid + rr*512;
    const float4* rp = (const float4*)(slab + (size_t)r*12);
    float4 x0 = rp[0], x1 = rp[1], x2 = rp[2];
    *(float4*)(qf + r*4) = x0;
    *(uint4*)(kvu + r*4) = make_uint4(pkh(x1.x,x1.y), pkh(x1.z,x1.w),
                                      pkh(x2.x,x2.y), pkh(x2.z,x2.w));
  }
  __syncthreads();
  int qa = qt*128 + ql, qb = qa + 64;
  const float S2 = 0.70710678f;      // 1/sqrt(Dh=2)
  float4 qav = *(const float4*)(qf + qa*4);
  float4 qbv = *(const float4*)(qf + qb*4);
  uint qa01 = pkh(qav.x*S2, qav.y*S2), qa23 = pkh(qav.z*S2, qav.w*S2);
  uint qb01 = pkh(qbv.x*S2, qbv.y*S2), qb23 = pkh(qbv.z*S2, qbv.w*S2);
  float la0=0.f, la1=0.f, aa00=0.f, aa01=0.f, aa10=0.f, aa11=0.f;
  float lb0=0.f, lb1=0.f, ab00=0.f, ab01=0.f, ab10=0.f, ab11=0.f;
  int kbeg = wv*128;
  #pragma unroll 4
  for (int k = kbeg; k < kbeg + 128; ++k) {
    uint4 kk = *(const uint4*)(kvu + k*4);   // uniform addr -> broadcast, 1 b128
    h2 k01 = toh2(kk.x), k23 = toh2(kk.y);
    h2 v01 = toh2(kk.z), v23 = toh2(kk.w);
    float pa0 = __expf(dot2h(toh2(qa01), k01, 0.f));
    float pa1 = __expf(dot2h(toh2(qa23), k23, 0.f));
    float pb0 = __expf(dot2h(toh2(qb01), k01, 0.f));
    float pb1 = __expf(dot2h(toh2(qb23), k23, 0.f));
    la0 += pa0; aa00 += pa0*(float)v01.x; aa01 += pa0*(float)v01.y;
    la1 += pa1; aa10 += pa1*(float)v23.x; aa11 += pa1*(float)v23.y;
    lb0 += pb0; ab00 += pb0*(float)v01.x; ab01 += pb0*(float)v01.y;
    lb1 += pb1; ab10 += pb1*(float)v23.x; ab11 += pb1*(float)v23.y;
  }
  float* ra = red + ql*49 + wv*6;
  ra[0]=la0; ra[1]=la1; ra[2]=aa00; ra[3]=aa01; ra[4]=aa10; ra[5]=aa11;
  float* rb = red + (ql+64)*49 + wv*6;
  rb[0]=lb0; rb[1]=lb1; rb[2]=ab00; rb[3]=ab01; rb[4]=ab10; rb[5]=ab11;
  __syncthreads();
  if (tid < 128) {
    float s[6] = {0.f,0.f,0.f,0.f,0.f,0.f};
    #pragma unroll
    for (int w = 0; w < 8; ++w) {
      const float* p = red + tid*49 + w*6;
      #pragma unroll
      for (int c = 0; c < 6; ++c) s[c] += p[c];
    }
    float r0 = rcpf(s[0]), r1 = rcpf(s[1]);
    float o[4] = { s[2]*r0, s[3]*r0, s[4]*r1, s[5]*r1 };
    int q2 = qt*128 + tid;
    const float* pWo = params + P_WOBLK + i*16;
    float* outp = all_blocks + (size_t)(b*TT + q2)*64 + i*4;
    #pragma unroll
    for (int j = 0; j < 4; ++j) {
      float a = params[P_BOBLK + i*4 + j];
      #pragma unroll
      for (int m2 = 0; m2 < 4; ++m2) a += pWo[j*4 + m2] * o[m2];
      outp[j] = a;
    }
  }
}

// ---------- K3: cross QKV projection, LDS-staged transposed weights ----------
__global__ void __launch_bounds__(256) k_qkv_c2(
    const float* __restrict__ all_blocks,
    const float* __restrict__ params,
    float* __restrict__ qkv_c) {
  __shared__ float w[12288];         // WqkvcT [64 j][192 c], 48 KB
  __shared__ float xs[256];
  int tid = threadIdx.x;
  int t0 = blockIdx.x * 4;           // grid 1024, wave per token
  {
    const float4* src = (const float4*)(params + P_WQCT);
    float4* dst = (float4*)w;
    #pragma unroll
    for (int i = tid; i < 3072; i += 256) dst[i] = src[i];
  }
  xs[tid] = all_blocks[t0*64 + tid];
  __syncthreads();
  int tt = tid >> 6, lane = tid & 63;
  int t = t0 + tt;
  const float* x = xs + tt*64;
  float a0 = params[P_BQC + lane];
  float a1 = params[P_BQC + 64 + lane];
  float a2 = params[P_BQC + 128 + lane];
  #pragma unroll 8
  for (int j = 0; j < 64; ++j) {
    const float* r = w + j*192;
    float xj = x[j];                           // LDS broadcast
    a0 += r[lane]       * xj;                  // stride-1 LDS, conflict-free
    a1 += r[64 + lane]  * xj;
    a2 += r[128 + lane] * xj;
  }
  float* o = qkv_c + (size_t)t*192;
  o[lane] = a0; o[64 + lane] = a1; o[128 + lane] = a2;
}

// ---------- K4: cross attention + fused recv; packed-f16 K/V (1 b128 each),
//             16 waves, 16-way key-split, 2 q/lane; recv uses exp2(s*L2E - log2 l) ----------
__global__ void __launch_bounds__(1024) k_cross9(
    const float* __restrict__ qkv_c,
    float* __restrict__ acc_c,
    float* __restrict__ recv_part) {
  // LDS arena (92.5 KB, u32 units):
  //   Ku  : [0     .. 4096)   [1024 k][4 u32] packed f16 K (live through recv)
  //   Vu  : [4096  .. 8192)   [1024 k][4 u32] packed f16 V (dead after main loop)
  //   red : [4096  .. 22656)  [128 q][145] f32 (overlays V)
  //   qbuf: [22656 .. 23680)  [128 q][8 u32]: 4 packed-q u32, [4] = -log2(l) f32
  __shared__ __align__(16) uint lds[23680];
  uint*  Ku  = lds;
  uint*  Vu  = lds + 4096;
  float* red = (float*)(lds + 4096);
  uint*  qb_ = lds + 22656;
  int bid = blockIdx.x;              // grid 256 = 4b * 8h * 8qt
  int qt = bid & 7, h = (bid >> 3) & 7, b = bid >> 6;
  int tid = threadIdx.x;
  int wv = __builtin_amdgcn_readfirstlane(tid) >> 6;   // 0..15
  int ql = tid & 63;
  int h8 = h*8;
  const float* base = qkv_c + (size_t)b*TT*192;
  // stage K and V, f32 -> packed f16
  {
    int r = tid;
    const float4* kp = (const float4*)(base + (size_t)r*192 + 64 + h8);
    const float4* vp = (const float4*)(base + (size_t)r*192 + 128 + h8);
    float4 k0 = kp[0], k1 = kp[1], v0 = vp[0], v1 = vp[1];
    *(uint4*)(Ku + r*4) = make_uint4(pkh(k0.x,k0.y), pkh(k0.z,k0.w),
                                     pkh(k1.x,k1.y), pkh(k1.z,k1.w));
    *(uint4*)(Vu + r*4) = make_uint4(pkh(v0.x,v0.y), pkh(v0.z,v0.w),
                                     pkh(v1.x,v1.y), pkh(v1.z,v1.w));
  }
  int qa = qt*128 + ql, qbq = qa + 64;
  const float SC = 0.35355339f;      // 1/sqrt(8)
  uint qa01,qa23,qa45,qa67, qb01,qb23,qb45,qb67;
  {
    const float4* pa = (const float4*)(base + (size_t)qa*192 + h8);
    const float4* pb = (const float4*)(base + (size_t)qbq*192 + h8);
    float4 a0 = pa[0], a1 = pa[1], b0 = pb[0], b1 = pb[1];
    qa01 = pkh(a0.x*SC, a0.y*SC); qa23 = pkh(a0.z*SC, a0.w*SC);
    qa45 = pkh(a1.x*SC, a1.y*SC); qa67 = pkh(a1.z*SC, a1.w*SC);
    qb01 = pkh(b0.x*SC, b0.y*SC); qb23 = pkh(b0.z*SC, b0.w*SC);
    qb45 = pkh(b1.x*SC, b1.y*SC); qb67 = pkh(b1.z*SC, b1.w*SC);
  }
  __syncthreads();
  float la = 0.f, lb = 0.f, aca[8], acb[8];
  #pragma unroll
  for (int c = 0; c < 8; ++c) { aca[c] = 0.f; acb[c] = 0.f; }
  int kbeg = wv*64;
  #pragma unroll 4
  for (int k = kbeg; k < kbeg + 64; ++k) {
    uint4 kk = *(const uint4*)(Ku + k*4);    // uniform -> broadcast, 1 b128
    uint4 vv = *(const uint4*)(Vu + k*4);
    h2 k01 = toh2(kk.x), k23 = toh2(kk.y), k45 = toh2(kk.z), k67 = toh2(kk.w);
    float sa = dot2h(toh2(qa01),k01, dot2h(toh2(qa23),k23,
               dot2h(toh2(qa45),k45, dot2h(toh2(qa67),k67, 0.f))));
    float sb = dot2h(toh2(qb01),k01, dot2h(toh2(qb23),k23,
               dot2h(toh2(qb45),k45, dot2h(toh2(qb67),k67, 0.f))));
    float pa = __expf(sa);
    float pb = __expf(sb);
    la += pa; lb += pb;
    h2 v01 = toh2(vv.x), v23 = toh2(vv.y), v45 = toh2(vv.z), v67 = toh2(vv.w);
    aca[0] += pa*(float)v01.x; aca[1] += pa*(float)v01.y;
    aca[2] += pa*(float)v23.x; aca[3] += pa*(float)v23.y;
    aca[4] += pa*(float)v45.x; aca[5] += pa*(float)v45.y;
    aca[6] += pa*(float)v67.x; aca[7] += pa*(float)v67.y;
    acb[0] += pb*(float)v01.x; acb[1] += pb*(float)v01.y;
    acb[2] += pb*(float)v23.x; acb[3] += pb*(float)v23.y;
    acb[4] += pb*(float)v45.x; acb[5] += pb*(float)v45.y;
    acb[6] += pb*(float)v67.x; acb[7] += pb*(float)v67.y;
  }
  __syncthreads();                   // V reads done; red overlays V region
  {
    float* ra = red + ql*145 + wv*9;
    ra[0] = la;
    #pragma unroll
    for (int c = 0; c < 8; ++c) ra[1+c] = aca[c];
    float* rb = red + (ql+64)*145 + wv*9;
    rb[0] = lb;
    #pragma unroll
    for (int c = 0; c < 8; ++c) rb[1+c] = acb[c];
    if (wv == 0) {                   // wave 0 holds scaled packed q for all 128 queries
      *(uint4*)(qb_ + ql*8)      = make_uint4(qa01, qa23, qa45, qa67);
      *(uint4*)(qb_ + (ql+64)*8) = make_uint4(qb01, qb23, qb45, qb67);
    }
  }
  __syncthreads();
  if (tid < 128) {
    float ls = 0.f, as[8];
    #pragma unroll
    for (int c = 0; c < 8; ++c) as[c] = 0.f;
    #pragma unroll
    for (int w = 0; w < 16; ++w) {
      const float* p = red + tid*145 + w*9;
      ls += p[0];
      #pragma unroll
      for (int c = 0; c < 8; ++c) as[c] += p[1+c];
    }
    float invl = rcpf(ls);
    int q2 = qt*128 + tid;
    int idx = (b*8 + h)*TT + q2;
    float4 o0 = { as[0]*invl, as[1]*invl, as[2]*invl, as[3]*invl };
    float4 o1 = { as[4]*invl, as[5]*invl, as[6]*invl, as[7]*invl };
    float4* op = (float4*)(acc_c + (size_t)idx*8);
    op[0] = o0; op[1] = o1;          // normalized PV
    ((float*)(qb_ + tid*8))[4] = -__log2f(ls);   // mq = -log2(l)
  }
  __syncthreads();
  // recv pass: 2 keys/lane; waves split by query half (waves 0-7: q0..63, 8-15: q64..127)
  {
    int qh = wv >> 3, g = wv & 7;
    int p = g*64 + ql;               // 0..511; keys p, p+512
    uint4 ka = *(const uint4*)(Ku + p*4);
    uint4 kb = *(const uint4*)(Ku + (p+512)*4);
    h2 A0 = toh2(ka.x), A1 = toh2(ka.y), A2 = toh2(ka.z), A3 = toh2(ka.w);
    h2 B0 = toh2(kb.x), B1 = toh2(kb.y), B2 = toh2(kb.z), B3 = toh2(kb.w);
    float r0 = 0.f, r1 = 0.f;
    const uint* qrow = qb_ + qh*64*8;
    const float L2E = 1.44269504f;
    #pragma unroll 4
    for (int qq = 0; qq < 64; ++qq) {
      uint4 q4 = *(const uint4*)(qrow + qq*8);   // uniform -> broadcast
      float mq = __uint_as_float(qrow[qq*8 + 4]);
      h2 Q0 = toh2(q4.x), Q1 = toh2(q4.y), Q2 = toh2(q4.z), Q3 = toh2(q4.w);
      float s0 = dot2h(Q0,A0, dot2h(Q1,A1, dot2h(Q2,A2, dot2h(Q3,A3, 0.f))));
      float s1 = dot2h(Q0,B0, dot2h(Q1,B1, dot2h(Q2,B2, dot2h(Q3,B3, 0.f))));
      r0 += exp2f(fmaf(s0, L2E, mq));            // = exp(s0)/l(q)
      r1 += exp2f(fmaf(s1, L2E, mq));
    }
    int src = h*16 + qt*2 + qh;      // 0..127, unique per (h,qt,query-half)
    recv_part[((size_t)(b*1024 + p      ))*128 + src] = r0;
    recv_part[((size_t)(b*1024 + p + 512))*128 + src] = r1;
  }
}

// ---------- K5: finalize-cross only (Wo_c^T projection, residual, LN1) ----------
__global__ void __launch_bounds__(256) k_fin(
    const float* __restrict__ all_blocks,
    const float* __restrict__ acc_c,
    const float* __restrict__ params,
    float* __restrict__ ln1) {
  __shared__ float pvs[4*64];
  int tt = threadIdx.x >> 6, j = threadIdx.x & 63;
  int t = blockIdx.x*4 + tt;         // grid 1024
  int b = t >> 10, tl = t & 1023;
  int h = j >> 3;
  int idx = (b*8 + h)*TT + tl;
  pvs[tt*64 + j] = acc_c[idx*8 + (j & 7)];
  __syncthreads();
  float a = params[P_BOC + j];
  const float* WoT = params + P_WOCT;          // [m][64]
  const float* p = pvs + tt*64;
  #pragma unroll 8
  for (int m = 0; m < 64; ++m) a += WoT[m*64 + j] * p[m];   // coalesced + broadcast
  float x = all_blocks[t*64 + j] + a;
  float s = x, s2 = x*x;
  #pragma unroll
  for (int off = 32; off; off >>= 1) { s += __shfl_xor(s, off); s2 += __shfl_xor(s2, off); }
  float mu  = s  * (1.f/64.f);
  float var = s2 * (1.f/64.f) - mu*mu;
  float y = (x - mu) * rsqrtf(var + 1e-5f) * params[P_G1 + j] + params[P_BE1 + j];
  ln1[t*64 + j] = y;
}

// ---------- K6: FFN + LN2 + recv-reduce + gate + un-blocking; LDS-staged W1T/W2T ----------
template <bool ISBF>
__global__ void __launch_bounds__(512) k_ffn_out2(
    const void* __restrict__ M,
    const float* __restrict__ ln1,
    const float* __restrict__ params,
    const float* __restrict__ blocks,
    const int* __restrict__ tok32,
    const float* __restrict__ recv_part,
    const void* __restrict__ sens_emb,
    void* __restrict__ out) {
  if (detect_bf16(M) != ISBF) return;
  __shared__ float w[16384];     // W1T, then re-staged as W2T (64 KB)
  __shared__ float ld2[512];     // [j][tok8]
  __shared__ float hbuf[2048];   // [tok8][256]
  int tid = threadIdx.x;
  int t0 = blockIdx.x * 8;       // grid 512, 8 tokens per block
  int wv = tid >> 6, lane = tid & 63;
  // recv reduce (wave per token), result kept in a register for phase 2
  float recv;
  {
    int t = t0 + wv, b = t >> 10, k = t & 1023;
    const float* rp = recv_part + ((size_t)(b*1024 + k))*128;
    float s = rp[lane] + rp[lane + 64];
    #pragma unroll
    for (int off = 32; off; off >>= 1) s += __shfl_xor(s, off);
    recv = s * (1.f/8192.f);     // /(H=8 * T=1024)
  }
  ld2[lane*8 + wv] = ln1[(t0 + wv)*64 + lane];
  {
    const float4* src = (const float4*)(params + P_W1T);
    float4* dst = (float4*)w;
    #pragma unroll
    for (int i = tid; i < 4096; i += 512) dst[i] = src[i];
  }
  __syncthreads();
  // phase 1: hidden = gelu(ln1 @ W1^T + b1); half-block g handles tokens g*4..g*4+3
  {
    int g = tid >> 8, u = tid & 255;
    float a0, a1, a2, a3;
    a0 = a1 = a2 = a3 = params[P_B1 + u];
    #pragma unroll 8
    for (int j = 0; j < 64; ++j) {
      float wj = w[j*256 + u];                     // stride-1 LDS
      float4 xj = *(const float4*)(ld2 + j*8 + g*4); // broadcast b128
      a0 += wj*xj.x; a1 += wj*xj.y; a2 += wj*xj.z; a3 += wj*xj.w;
    }
    float av[4] = {a0, a1, a2, a3};
    #pragma unroll
    for (int t2 = 0; t2 < 4; ++t2) {
      float v = av[t2];
      float u2 = 1.5957691f*v + 0.07135481f*v*v*v;   // tanh-GELU sigmoid form
      hbuf[(g*4 + t2)*256 + u] = v * rcpf(1.f + __expf(-u2));
    }
  }
  __syncthreads();
  // re-stage W2T over the same arena
  {
    const float4* src = (const float4*)(params + P_W2T);
    float4* dst = (float4*)w;
    #pragma unroll
    for (int i = tid; i < 4096; i += 512) dst[i] = src[i];
  }
  __syncthreads();
  // phase 2: y = hidden @ W2^T + b2 (wave per token); LN2; gate; un-block
  int j = lane;
  int t = t0 + wv, b = t >> 10;
  float y = params[P_B2 + j];
  const float* hb = hbuf + wv*256;
  #pragma unroll 8
  for (int k = 0; k < 256; ++k) y += w[k*64 + j] * hb[k];   // stride-1 LDS + broadcast
  float z = ld2[j*8 + wv] + y;
  float s = z, s2 = z*z;
  #pragma unroll
  for (int off = 32; off; off >>= 1) { s += __shfl_xor(s, off); s2 += __shfl_xor(s2, off); }
  float mu  = s  * (1.f/64.f);
  float var = s2 * (1.f/64.f) - mu*mu;
  float y2 = (z - mu) * rsqrtf(var + 1e-5f) * params[P_G2 + j] + params[P_BE2 + j];
  bool is64 = ((tok32[1] | tok32[3] | tok32[5] | tok32[7]) == 0);
  int tok = is64 ? tok32[t*2] : tok32[t];
  int i = j >> 2, e = j & 3;
  float sv = ldf<ISBF>(sens_emb, tok*16 + i) + recv * params[P_SAL + i];
  float sg = rcpf(1.f + __expf(-sv));
  float blk = blocks[t*64 + j];
  float nb = blk + (y2 - blk) * sg;
  int rb = i >> 2, cb = i & 3, r = e >> 1, c = e & 1;
  int oidx = t*64 + (rb*2 + r)*8 + cb*2 + c;
  if (ISBF) ((__hip_bfloat16*)out)[oidx] = __float2bfloat16(nb);
  else      ((float*)out)[oidx] = nb;
}

extern "C" void kernel_launch(void* const* d_in, const int* in_sizes, int n_in,
                              void* d_out, int out_size, void* d_ws, size_t ws_size,
                              hipStream_t stream) {
  const void* M        = d_in[0];
  const int*  tok      = (const int*)d_in[1];
  const void* Wqkv_blk = d_in[2];
  const void* bqkv_blk = d_in[3];
  const void* Wo_blk   = d_in[4];
  const void* bo_blk   = d_in[5];
  const void* Wqkv_c   = d_in[6];
  const void* bqkv_c   = d_in[7];
  const void* Wo_c     = d_in[8];
  const void* bo_c     = d_in[9];
  const void* W1       = d_in[10];
  const void* b1       = d_in[11];
  const void* W2       = d_in[12];
  const void* b2       = d_in[13];
  const void* g1       = d_in[14];
  const void* be1      = d_in[15];
  const void* g2i      = d_in[16];
  const void* be2      = d_in[17];
  const void* sens_emb = d_in[18];
  const void* sens_al  = d_in[19];

  float* ws = (float*)d_ws;
  float* blocks    = ws + OFF_BLOCKS;
  float* qkv_blk   = ws + OFF_QKVB;
  float* recv_part = ws + OFF_RECVP;   // aliases qkv_blk (dead after k_blk2)
  float* all_blk   = ws + OFF_ALLB;
  float* qkv_c     = ws + OFF_QKVC;
  float* acc_c     = ws + OFF_ACCC;
  float* ln1       = ws + OFF_LN1;
  float* params    = ws + OFF_PARAMS;

  k_prep2<true ><<<272, 256, 0, stream>>>(M, Wqkv_blk, bqkv_blk, W1, W2, Wqkv_c, Wo_c,
                                          Wo_blk, bo_blk, bqkv_c, bo_c, g1, be1, b1, b2,
                                          g2i, be2, sens_al, blocks, qkv_blk, params);
  k_prep2<false><<<272, 256, 0, stream>>>(M, Wqkv_blk, bqkv_blk, W1, W2, Wqkv_c, Wo_c,
                                          Wo_blk, bo_blk, bqkv_c, bo_c, g1, be1, b1, b2,
                                          g2i, be2, sens_al, blocks, qkv_blk, params);
  k_blk2<<<512, 512, 0, stream>>>(qkv_blk, params, all_blk);
  k_qkv_c2<<<1024, 256, 0, stream>>>(all_blk, params, qkv_c);
  k_cross9<<<256, 1024, 0, stream>>>(qkv_c, acc_c, recv_part);
  k_fin<<<1024, 256, 0, stream>>>(all_blk, acc_c, params, ln1);
  k_ffn_out2<true ><<<512, 512, 0, stream>>>(M, ln1, params, blocks, tok, recv_part,
                                             sens_emb, (void*)d_out);
  k_ffn_out2<false><<<512, 512, 0, stream>>>(M, ln1, params, blocks, tok, recv_part,
                                             sens_emb, (void*)d_out);
}